// Round 5
// baseline (355.363 us; speedup 1.0000x reference)
//
#include <hip/hip_runtime.h>
#include <math.h>

#define NN 50000
#define EE 800000
#define GG 512
#define OUTC 100
#define NEG 0.2f
#define STRIDE 64
#define NPART 8
#define PRNG (NN / NPART)           // 6250
#define PCHUNK 2048
#define NCHUNK 391                  // 391*2048 >= 800000
#define SCAT_BLOCKS (NPART * NCHUNK)   // 3128, %8==0

// weight block layout: 32 sub-blocks (16 hi + 16 lo) x WROWS rows x 8 ushorts.
#define WROWS 145
#define WCHUNKS 73
#define WLAYER (WCHUNKS * 512)

typedef unsigned int u32;
#define GLOBAL_AS __attribute__((address_space(1)))
#define LDS_AS __attribute__((address_space(3)))

typedef __attribute__((ext_vector_type(8))) short bf16x8;
typedef __attribute__((ext_vector_type(8))) short s16x8;
typedef __attribute__((ext_vector_type(8))) unsigned short us8;
typedef __attribute__((ext_vector_type(4))) float f32x4;
typedef __attribute__((ext_vector_type(4))) int i32x4;

__device__ inline ushort f2bf(float v) {
  unsigned u = __float_as_uint(v);
  unsigned r = (u + 0x7fff + ((u >> 16) & 1)) >> 16;
  return (ushort)r;
}

// ---- dst-partitioned scatter (unconditional early src loads, NT streams) + weight prep ----
__global__ __launch_bounds__(256) void k_scatter_prep(const int* __restrict__ ei,
    int* __restrict__ cursor, ushort* __restrict__ srcs,
    const float* __restrict__ W0, const float* __restrict__ W1, const float* __restrict__ W2,
    const float* __restrict__ as0, const float* __restrict__ as1, const float* __restrict__ as2,
    const float* __restrict__ ad0, const float* __restrict__ ad1, const float* __restrict__ ad2,
    ushort* __restrict__ wg) {
  if (blockIdx.x < SCAT_BLOCKS) {
    int part = blockIdx.x & (NPART - 1);     // == XCD under round-robin placement
    int chunk = blockIdx.x >> 3;
    int plo = part * PRNG, phi = plo + PRNG;
    int base = chunk * PCHUNK + (threadIdx.x << 2);
    bool l0 = base < EE, l1 = (base + 1024) < EE;
    i32x4 d0, d1, s0, s1;
    // all 4 loads issued up-front: src does NOT wait on dst (chain 2.3k->1.4k cyc).
    // nontemporal: don't let the streaming edge reads evict the partition's
    // 800KB srcs write-window from this XCD's L2.
    if (l0) {
      d0 = __builtin_nontemporal_load((const i32x4*)&ei[EE + base]);
      s0 = __builtin_nontemporal_load((const i32x4*)&ei[base]);
    }
    if (l1) {
      d1 = __builtin_nontemporal_load((const i32x4*)&ei[EE + base + 1024]);
      s1 = __builtin_nontemporal_load((const i32x4*)&ei[base + 1024]);
    }
#define SCAT1(DV, SV) do { \
      if ((DV) >= plo && (DV) < phi) { \
        int ppos = atomicAdd(&cursor[DV], 1); \
        if (ppos < STRIDE) srcs[((unsigned)(DV) << 6) + ppos] = (ushort)(SV); \
      } } while (0)
    if (l0) {
      SCAT1(d0.x, s0.x); SCAT1(d0.y, s0.y); SCAT1(d0.z, s0.z); SCAT1(d0.w, s0.w);
    }
    if (l1) {
      SCAT1(d1.x, s1.x); SCAT1(d1.y, s1.y); SCAT1(d1.z, s1.z); SCAT1(d1.w, s1.w);
    }
#undef SCAT1
  } else {
    int pb = blockIdx.x - SCAT_BLOCKS;          // 0..203
    int layer = pb / 68, bx = pb % 68;
    const float* W  = (layer == 0) ? W0 : (layer == 1) ? W1 : W2;
    const float* av = (layer == 0) ? as0 : (layer == 1) ? as1 : as2;
    const float* dv = (layer == 0) ? ad0 : (layer == 1) ? ad1 : ad2;
    ushort* wgL = wg + (size_t)layer * WLAYER;
    int idx = bx * 256 + threadIdx.x;
    if (bx < 64) {
      int row = idx >> 7, col = idx & 127;
      int c = col >> 3, j = col & 7;
      float v = W[idx];
      ushort hb = f2bf(v);
      float hf = __uint_as_float(((unsigned)hb) << 16);
      wgL[((size_t)c * WROWS + row) * 8 + j] = hb;
      wgL[((size_t)(16 + c) * WROWS + row) * 8 + j] = f2bf(v - hf);
    } else {
      int j2 = idx - 64 * 256;                  // [0,1024)
      int j = j2 >> 7, k = j2 & 127;            // j: attn row 0..7, k: col
      int head = j & 3;
      const float* vec = (j < 4) ? &av[head * 32] : &dv[head * 32];
      float dot = 0.f;
#pragma unroll
      for (int c = 0; c < 32; c++) dot += W[(head * 32 + c) * 128 + k] * vec[c];
      ushort hb = f2bf(dot);
      float hf = __uint_as_float(((unsigned)hb) << 16);
      int c16 = k >> 3, jj = k & 7;
      wgL[((size_t)c16 * WROWS + 128 + j) * 8 + jj] = hb;
      wgL[((size_t)(16 + c16) * WROWS + 128 + j) * 8 + jj] = f2bf(dot - hf);
      wgL[((size_t)c16 * WROWS + 136 + j) * 8 + jj] = 0;
      wgL[((size_t)(16 + c16) * WROWS + 136 + j) * 8 + jj] = 0;
    }
  }
}

// ---------------- GEMM: weights staged in LDS, feat hoisted to regs ----------------
__global__ __launch_bounds__(512) void k_gemm_mfma(const float* __restrict__ feat,
    const ushort* __restrict__ wg,
    short* __restrict__ hq, float* __restrict__ asp, float* __restrict__ adstf) {
  __shared__ alignas(16) ushort lds[WLAYER];
  int t = threadIdx.x;
  int wave = t >> 6, lane = t & 63;
  int quad = lane >> 4, r16 = lane & 15;

#pragma unroll
  for (int i = 0; i < 10; ++i) {
    int chunk = i * 8 + wave;
    if (chunk < WCHUNKS) {
      int off = chunk * 512 + lane * 8;
      __builtin_amdgcn_global_load_lds((const GLOBAL_AS u32*)&wg[off],
                                       (LDS_AS u32*)&lds[off], 16, 0, 0);
    }
  }

  int n0 = blockIdx.x * 128;
  int rowA = n0 + wave * 16 + r16;
  bool valid = rowA < NN;
  float4 f[8];
#pragma unroll
  for (int ks = 0; ks < 4; ++ks) {
    if (valid) {
      const float4* fp = (const float4*)&feat[(size_t)rowA * 128 + ks * 32 + quad * 8];
      f[ks * 2] = fp[0];
      f[ks * 2 + 1] = fp[1];
    } else {
      f[ks * 2] = make_float4(0.f, 0.f, 0.f, 0.f);
      f[ks * 2 + 1] = f[ks * 2];
    }
  }
  __syncthreads();

  f32x4 acc[9];
#pragma unroll
  for (int nt = 0; nt < 9; nt++) acc[nt] = (f32x4)0.f;

#pragma unroll
  for (int ks = 0; ks < 4; ks++) {
    bf16x8 ah, al;
    {
      float4 va = f[ks * 2], vb = f[ks * 2 + 1];
      float vv[8] = {va.x, va.y, va.z, va.w, vb.x, vb.y, vb.z, vb.w};
      us8 hh, ll;
#pragma unroll
      for (int j = 0; j < 8; j++) {
        ushort hb = f2bf(vv[j]);
        float hf = __uint_as_float(((unsigned)hb) << 16);
        hh[j] = hb;
        ll[j] = (ushort)(__float_as_uint(vv[j] - hf) >> 16);
      }
      ah = (bf16x8)hh;
      al = (bf16x8)ll;
    }
    int cc = ks * 4 + quad;
#pragma unroll
    for (int nt = 0; nt < 9; nt++) {
      int wrow = (nt < 8) ? (nt * 16 + r16) : (128 + r16);
      bf16x8 bh = *(const bf16x8*)&lds[((size_t)cc * WROWS + wrow) * 8];
      bf16x8 bl = *(const bf16x8*)&lds[((size_t)(16 + cc) * WROWS + wrow) * 8];
      acc[nt] = __builtin_amdgcn_mfma_f32_16x16x32_bf16(ah, bh, acc[nt], 0, 0, 0);
      acc[nt] = __builtin_amdgcn_mfma_f32_16x16x32_bf16(al, bh, acc[nt], 0, 0, 0);
      acc[nt] = __builtin_amdgcn_mfma_f32_16x16x32_bf16(ah, bl, acc[nt], 0, 0, 0);
    }
  }

#pragma unroll
  for (int reg = 0; reg < 4; reg++) {
    float am = 0.f;
#pragma unroll
    for (int nt = 0; nt < 8; nt++) am = fmaxf(am, fabsf(acc[nt][reg]));
#pragma unroll
    for (int off = 1; off < 16; off <<= 1) am = fmaxf(am, __shfl_xor(am, off));
    int node = n0 + wave * 16 + quad * 4 + reg;
    if (node < NN) {
      float amc = fmaxf(am, 1e-20f);
      float rq = 32767.f / amc;
      if (r16 < 4) asp[node * 8 + r16] = acc[8][reg];
      else if (r16 < 8) adstf[node * 4 + r16 - 4] = acc[8][reg];
      else if (r16 == 8) asp[node * 8 + 4] = amc * (1.f / 32767.f);
      short* dq = &hq[(size_t)node * 128 + r16];
#pragma unroll
      for (int nt = 0; nt < 8; nt++)
        dq[nt * 16] = (short)__float2int_rn(acc[nt][reg] * rq);
    }
  }
}

// ---------------- gather-aggregate (FUSE=1: layer-3 + mean-pool fusion) ----------------
template <int FUSE>
__device__ __forceinline__ void gather_core(const short* __restrict__ hq,
    const float* __restrict__ asp, const float4* __restrict__ adst,
    const int* __restrict__ cursor, const ushort* __restrict__ srcs,
    const float* __restrict__ bias, float* __restrict__ outf,
    const int* __restrict__ batchv, float* __restrict__ pooled, float* __restrict__ cnt) {
  __shared__ alignas(16) int   s_src[2][4][4][16];
  __shared__ alignas(16) float s_wt[2][4][4][4][20];

  int wave = threadIdx.x >> 6, lane = threadIdx.x & 63;
  int grp = lane >> 4;
  int gl = lane & 15;
  int node = blockIdx.x * 16 + wave * 4 + grp;
  int head = gl >> 2;
  int c0 = gl << 3;

  int deg = 0, e0 = 0;
  float4 ad = make_float4(0.f, 0.f, 0.f, 0.f);
  bool valid = node < NN;
  if (valid) {
    deg = min(cursor[node], STRIDE);
    e0 = node << 6;
    ad = adst[node];
  }
  int rounds = (deg + 15) >> 4;

  float acc[8];
#pragma unroll
  for (int i = 0; i < 8; i++) acc[i] = 0.f;
  float ws0 = 0.f, ws1 = 0.f, ws2 = 0.f, ws3 = 0.f;
  float wself = 0.f;

  int nsn = 0, nlive = 0;

  auto phase1 = [&](int r) {
    int j = (r << 4) + gl;
    nlive = (j < deg);
    nsn = nlive ? (int)srcs[e0 + j] : 0;
  };

  auto phase2 = [&](int b) {
    float q0 = 0.f, q1 = 0.f, q2 = 0.f, q3 = 0.f;
    if (nlive) {
      const float4 a = *(const float4*)&asp[nsn * 8];
      float sc = asp[nsn * 8 + 4];
      float v, w0, w1, w2, w3;
      v = a.x + ad.x; v = v > 0.f ? v : NEG * v; w0 = __expf(v);
      v = a.y + ad.y; v = v > 0.f ? v : NEG * v; w1 = __expf(v);
      v = a.z + ad.z; v = v > 0.f ? v : NEG * v; w2 = __expf(v);
      v = a.w + ad.w; v = v > 0.f ? v : NEG * v; w3 = __expf(v);
      ws0 += w0; ws1 += w1; ws2 += w2; ws3 += w3;
      q0 = w0 * sc; q1 = w1 * sc; q2 = w2 * sc; q3 = w3 * sc;
    }
    s_src[b][wave][grp][gl] = nsn << 7;
    s_wt[b][wave][grp][0][gl] = q0;
    s_wt[b][wave][grp][1][gl] = q1;
    s_wt[b][wave][grp][2][gl] = q2;
    s_wt[b][wave][grp][3][gl] = q3;
  };

  auto consume = [&](int r, int b) {
    int cnt2 = deg - (r << 4);
    cnt2 = min(cnt2, 16);
    const int* srow = &s_src[b][wave][grp][0];
    const float* wrow = &s_wt[b][wave][grp][head][0];
#pragma unroll
    for (int c = 0; c < 2; ++c) {
      int k0 = c << 3;
      if (k0 < cnt2) {
        int4 sa = *(const int4*)&srow[k0];
        int4 sb = *(const int4*)&srow[k0 + 4];
        float4 wa = *(const float4*)&wrow[k0];
        float4 wb = *(const float4*)&wrow[k0 + 4];
        s16x8 qa = *(const s16x8*)&hq[sa.x + c0];
        s16x8 qb = *(const s16x8*)&hq[sa.y + c0];
        s16x8 qc = *(const s16x8*)&hq[sa.z + c0];
        s16x8 qd = *(const s16x8*)&hq[sa.w + c0];
        s16x8 qe = *(const s16x8*)&hq[sb.x + c0];
        s16x8 qf = *(const s16x8*)&hq[sb.y + c0];
        s16x8 qg = *(const s16x8*)&hq[sb.z + c0];
        s16x8 qh = *(const s16x8*)&hq[sb.w + c0];
#pragma unroll
        for (int i = 0; i < 8; i++) acc[i] = fmaf(wa.x, (float)qa[i], acc[i]);
#pragma unroll
        for (int i = 0; i < 8; i++) acc[i] = fmaf(wa.y, (float)qb[i], acc[i]);
#pragma unroll
        for (int i = 0; i < 8; i++) acc[i] = fmaf(wa.z, (float)qc[i], acc[i]);
#pragma unroll
        for (int i = 0; i < 8; i++) acc[i] = fmaf(wa.w, (float)qd[i], acc[i]);
        if (k0 + 4 < cnt2) {
#pragma unroll
          for (int i = 0; i < 8; i++) acc[i] = fmaf(wb.x, (float)qe[i], acc[i]);
#pragma unroll
          for (int i = 0; i < 8; i++) acc[i] = fmaf(wb.y, (float)qf[i], acc[i]);
#pragma unroll
          for (int i = 0; i < 8; i++) acc[i] = fmaf(wb.z, (float)qg[i], acc[i]);
#pragma unroll
          for (int i = 0; i < 8; i++) acc[i] = fmaf(wb.w, (float)qh[i], acc[i]);
        }
      }
    }
  };

  phase1(0);

  if (valid) {
    const float4 a = *(const float4*)&asp[node * 8];
    float sc = asp[node * 8 + 4];
    float v, w0, w1, w2, w3;
    v = a.x + ad.x; v = v > 0.f ? v : NEG * v; w0 = __expf(v);
    v = a.y + ad.y; v = v > 0.f ? v : NEG * v; w1 = __expf(v);
    v = a.z + ad.z; v = v > 0.f ? v : NEG * v; w2 = __expf(v);
    v = a.w + ad.w; v = v > 0.f ? v : NEG * v; w3 = __expf(v);
    float wh = (head == 0) ? w0 : (head == 1) ? w1 : (head == 2) ? w2 : w3;
    wself = wh;
    float wssc = wh * sc;
    s16x8 qs = *(const s16x8*)&hq[(node << 7) + c0];
#pragma unroll
    for (int i = 0; i < 8; i++) acc[i] = wssc * (float)qs[i];
  }

  if (rounds > 0) {
    phase2(0);
    for (int r = 0; r < rounds; ++r) {
      int b = r & 1;
      if (r + 1 < rounds) phase1(r + 1);
      consume(r, b);
      if (r + 1 < rounds) phase2(b ^ 1);
    }
  }

#pragma unroll
  for (int off = 1; off < 16; off <<= 1) {
    ws0 += __shfl_xor(ws0, off);
    ws1 += __shfl_xor(ws1, off);
    ws2 += __shfl_xor(ws2, off);
    ws3 += __shfl_xor(ws3, off);
  }

  float o[8];
  if (valid) {
    float wsum = wself + ((head == 0) ? ws0 : (head == 1) ? ws1 : (head == 2) ? ws2 : ws3);
    float rcp = 1.f / (wsum + 1e-16f);
    float4 bv0 = *(const float4*)&bias[c0];
    float4 bv1 = *(const float4*)&bias[c0 + 4];
    float bb[8] = {bv0.x, bv0.y, bv0.z, bv0.w, bv1.x, bv1.y, bv1.z, bv1.w};
#pragma unroll
    for (int i = 0; i < 8; i++) {
      float v = acc[i] * rcp + bb[i];
      o[i] = v > 0.f ? v : expm1f(v);
    }
  } else {
#pragma unroll
    for (int i = 0; i < 8; i++) o[i] = 0.f;
  }

  if (!FUSE) {
    if (valid) {
      *(float4*)&outf[(size_t)node * 128 + c0] = make_float4(o[0], o[1], o[2], o[3]);
      *(float4*)&outf[(size_t)node * 128 + c0 + 4] = make_float4(o[4], o[5], o[6], o[7]);
    }
  } else {
    // mean-pool fusion: batch is sorted, so the wave's 4 nodes usually share a
    // graph -> reduce across groups (shfl 16,32), 1 atomic per 4 nodes.
    int g = valid ? batchv[node] : -1;
    int g1 = __shfl_xor(g, 16);
    int g2 = __shfl_xor(g, 32);
    int g3 = __shfl_xor(g, 48);
    bool uni = (g == g1) && (g == g2) && (g == g3) && (g >= 0);
    if (uni) {
#pragma unroll
      for (int i = 0; i < 8; i++) {
        float s = o[i];
        s += __shfl_xor(s, 16);
        s += __shfl_xor(s, 32);
        if (lane < 16) atomicAdd(&pooled[g * 128 + c0 + i], s);
      }
      if (lane == 0) atomicAdd(&cnt[g], 4.f);
    } else if (valid) {
#pragma unroll
      for (int i = 0; i < 8; i++) atomicAdd(&pooled[g * 128 + c0 + i], o[i]);
      if (gl == 0) atomicAdd(&cnt[g], 1.f);
    }
  }
}

__global__ __launch_bounds__(256) void k_gather(const short* __restrict__ hq,
    const float* __restrict__ asp, const float4* __restrict__ adst,
    const int* __restrict__ cursor, const ushort* __restrict__ srcs,
    const float* __restrict__ bias, float* __restrict__ outf) {
  gather_core<0>(hq, asp, adst, cursor, srcs, bias, outf, nullptr, nullptr, nullptr);
}

__global__ __launch_bounds__(256) void k_gather_pool(const short* __restrict__ hq,
    const float* __restrict__ asp, const float4* __restrict__ adst,
    const int* __restrict__ cursor, const ushort* __restrict__ srcs,
    const float* __restrict__ bias,
    const int* __restrict__ batchv, float* __restrict__ pooled, float* __restrict__ cnt) {
  gather_core<1>(hq, asp, adst, cursor, srcs, bias, nullptr, batchv, pooled, cnt);
}

// ---------------- final FC ----------------
__global__ __launch_bounds__(128) void k_fc(const float* __restrict__ pooled,
    const float* __restrict__ cnt, const float* __restrict__ fcW,
    const float* __restrict__ fcb, float* __restrict__ out) {
  int g = blockIdx.x;
  __shared__ float p[128];
  int t = threadIdx.x;
  float inv = 1.0f / fmaxf(cnt[g], 1.0f);
  p[t] = pooled[g * 128 + t] * inv;
  __syncthreads();
  if (t < OUTC) {
    float acc = fcb[t];
    const float4* wr = (const float4*)&fcW[t * 128];
    const float4* pp = (const float4*)p;
#pragma unroll
    for (int i = 0; i < 32; i++) {
      float4 w = wr[i], pv = pp[i];
      acc = fmaf(w.x, pv.x, fmaf(w.y, pv.y, fmaf(w.z, pv.z, fmaf(w.w, pv.w, acc))));
    }
    out[g * OUTC + t] = acc;
  }
}

extern "C" void kernel_launch(void* const* d_in, const int* in_sizes, int n_in,
                              void* d_out, int out_size, void* d_ws, size_t ws_size,
                              hipStream_t stream) {
  const float* x    = (const float*)d_in[0];
  const int*   ei   = (const int*)d_in[1];
  const int*   batch= (const int*)d_in[2];
  const float* W1   = (const float*)d_in[3];
  const float* as1  = (const float*)d_in[4];
  const float* ad1  = (const float*)d_in[5];
  const float* b1   = (const float*)d_in[6];
  const float* W2   = (const float*)d_in[7];
  const float* as2  = (const float*)d_in[8];
  const float* ad2  = (const float*)d_in[9];
  const float* b2   = (const float*)d_in[10];
  const float* W3   = (const float*)d_in[11];
  const float* as3  = (const float*)d_in[12];
  const float* ad3  = (const float*)d_in[13];
  const float* b3   = (const float*)d_in[14];
  const float* fcW  = (const float*)d_in[15];
  const float* fcb  = (const float*)d_in[16];
  float* out = (float*)d_out;

  char* p = (char*)d_ws;
  auto alloc = [&](size_t bytes) { char* r = p; p += (bytes + 255) & ~(size_t)255; return r; };
  short* hq     = (short*)alloc((size_t)NN * 128 * 2);
  float* asp    = (float*)alloc((size_t)NN * 8 * 4);
  float* buf0   = (float*)alloc((size_t)NN * 128 * 4);
  float* adstv  = (float*)alloc((size_t)NN * 4 * 4);
  char*  zbase  = p;
  int*   cursor = (int*)alloc((size_t)NN * 4);
  float* pooled = (float*)alloc((size_t)GG * 128 * 4);
  float* cnt    = (float*)alloc((size_t)GG * 4);
  size_t zlen   = (size_t)(p - zbase);
  ushort* srcs  = (ushort*)alloc((size_t)NN * STRIDE * 2);
  ushort* wg    = (ushort*)alloc((size_t)3 * WLAYER * 2);

  hipMemsetAsync(zbase, 0, zlen, stream);

  k_scatter_prep<<<SCAT_BLOCKS + 204, 256, 0, stream>>>(ei, cursor, srcs,
      W1, W2, W3, as1, as2, as3, ad1, ad2, ad3, wg);

  // layers 1,2: gather writes features; layer 3: gather fuses mean-pool
  k_gemm_mfma<<<(NN + 127) / 128, 512, 0, stream>>>(x, wg, hq, asp, adstv);
  k_gather<<<(NN + 15) / 16, 256, 0, stream>>>(hq, asp,
      (const float4*)adstv, cursor, srcs, b1, buf0);
  k_gemm_mfma<<<(NN + 127) / 128, 512, 0, stream>>>(buf0,
      wg + (size_t)WLAYER, hq, asp, adstv);
  k_gather<<<(NN + 15) / 16, 256, 0, stream>>>(hq, asp,
      (const float4*)adstv, cursor, srcs, b2, buf0);
  k_gemm_mfma<<<(NN + 127) / 128, 512, 0, stream>>>(buf0,
      wg + (size_t)2 * WLAYER, hq, asp, adstv);
  k_gather_pool<<<(NN + 15) / 16, 256, 0, stream>>>(hq, asp,
      (const float4*)adstv, cursor, srcs, b3, batch, pooled, cnt);

  k_fc<<<GG, 128, 0, stream>>>(pooled, cnt, fcW, fcb, out);
}

// Round 6
// 322.495 us; speedup vs baseline: 1.1019x; 1.1019x over previous
//
#include <hip/hip_runtime.h>
#include <math.h>

#define NN 50000
#define EE 800000
#define GG 512
#define OUTC 100
#define NEG 0.2f
#define STRIDE 64
#define NPART 8
#define PRNG (NN / NPART)           // 6250
#define PCHUNK 2048
#define NCHUNK 391                  // 391*2048 >= 800000
#define SCAT_BLOCKS (NPART * NCHUNK)   // 3128, %8==0

// weight block layout: 32 sub-blocks (16 hi + 16 lo) x WROWS rows x 8 ushorts.
#define WROWS 145
#define WCHUNKS 73
#define WLAYER (WCHUNKS * 512)

typedef unsigned int u32;
#define GLOBAL_AS __attribute__((address_space(1)))
#define LDS_AS __attribute__((address_space(3)))

typedef __attribute__((ext_vector_type(8))) short bf16x8;
typedef __attribute__((ext_vector_type(8))) short s16x8;
typedef __attribute__((ext_vector_type(8))) unsigned short us8;
typedef __attribute__((ext_vector_type(4))) float f32x4;
typedef __attribute__((ext_vector_type(4))) int i32x4;

__device__ inline ushort f2bf(float v) {
  unsigned u = __float_as_uint(v);
  unsigned r = (u + 0x7fff + ((u >> 16) & 1)) >> 16;
  return (ushort)r;
}

// ---- dst-partitioned scatter (unconditional early src loads, NT streams) + weight prep ----
__global__ __launch_bounds__(256) void k_scatter_prep(const int* __restrict__ ei,
    int* __restrict__ cursor, ushort* __restrict__ srcs,
    const float* __restrict__ W0, const float* __restrict__ W1, const float* __restrict__ W2,
    const float* __restrict__ as0, const float* __restrict__ as1, const float* __restrict__ as2,
    const float* __restrict__ ad0, const float* __restrict__ ad1, const float* __restrict__ ad2,
    ushort* __restrict__ wg) {
  if (blockIdx.x < SCAT_BLOCKS) {
    int part = blockIdx.x & (NPART - 1);     // == XCD under round-robin placement
    int chunk = blockIdx.x >> 3;
    int plo = part * PRNG, phi = plo + PRNG;
    int base = chunk * PCHUNK + (threadIdx.x << 2);
    bool l0 = base < EE, l1 = (base + 1024) < EE;
    i32x4 d0, d1, s0, s1;
    if (l0) {
      d0 = __builtin_nontemporal_load((const i32x4*)&ei[EE + base]);
      s0 = __builtin_nontemporal_load((const i32x4*)&ei[base]);
    }
    if (l1) {
      d1 = __builtin_nontemporal_load((const i32x4*)&ei[EE + base + 1024]);
      s1 = __builtin_nontemporal_load((const i32x4*)&ei[base + 1024]);
    }
#define SCAT1(DV, SV) do { \
      if ((DV) >= plo && (DV) < phi) { \
        int ppos = atomicAdd(&cursor[DV], 1); \
        if (ppos < STRIDE) srcs[((unsigned)(DV) << 6) + ppos] = (ushort)(SV); \
      } } while (0)
    if (l0) {
      SCAT1(d0.x, s0.x); SCAT1(d0.y, s0.y); SCAT1(d0.z, s0.z); SCAT1(d0.w, s0.w);
    }
    if (l1) {
      SCAT1(d1.x, s1.x); SCAT1(d1.y, s1.y); SCAT1(d1.z, s1.z); SCAT1(d1.w, s1.w);
    }
#undef SCAT1
  } else {
    int pb = blockIdx.x - SCAT_BLOCKS;          // 0..203
    int layer = pb / 68, bx = pb % 68;
    const float* W  = (layer == 0) ? W0 : (layer == 1) ? W1 : W2;
    const float* av = (layer == 0) ? as0 : (layer == 1) ? as1 : as2;
    const float* dv = (layer == 0) ? ad0 : (layer == 1) ? ad1 : ad2;
    ushort* wgL = wg + (size_t)layer * WLAYER;
    int idx = bx * 256 + threadIdx.x;
    if (bx < 64) {
      int row = idx >> 7, col = idx & 127;
      int c = col >> 3, j = col & 7;
      float v = W[idx];
      ushort hb = f2bf(v);
      float hf = __uint_as_float(((unsigned)hb) << 16);
      wgL[((size_t)c * WROWS + row) * 8 + j] = hb;
      wgL[((size_t)(16 + c) * WROWS + row) * 8 + j] = f2bf(v - hf);
    } else {
      int j2 = idx - 64 * 256;                  // [0,1024)
      int j = j2 >> 7, k = j2 & 127;            // j: attn row 0..7, k: col
      int head = j & 3;
      const float* vec = (j < 4) ? &av[head * 32] : &dv[head * 32];
      float dot = 0.f;
#pragma unroll
      for (int c = 0; c < 32; c++) dot += W[(head * 32 + c) * 128 + k] * vec[c];
      ushort hb = f2bf(dot);
      float hf = __uint_as_float(((unsigned)hb) << 16);
      int c16 = k >> 3, jj = k & 7;
      wgL[((size_t)c16 * WROWS + 128 + j) * 8 + jj] = hb;
      wgL[((size_t)(16 + c16) * WROWS + 128 + j) * 8 + jj] = f2bf(dot - hf);
      wgL[((size_t)c16 * WROWS + 136 + j) * 8 + jj] = 0;
      wgL[((size_t)(16 + c16) * WROWS + 136 + j) * 8 + jj] = 0;
    }
  }
}

// ---------------- GEMM: weights staged in LDS, feat hoisted to regs ----------------
__global__ __launch_bounds__(512) void k_gemm_mfma(const float* __restrict__ feat,
    const ushort* __restrict__ wg,
    short* __restrict__ hq, float* __restrict__ asp, float* __restrict__ adstf) {
  __shared__ alignas(16) ushort lds[WLAYER];
  int t = threadIdx.x;
  int wave = t >> 6, lane = t & 63;
  int quad = lane >> 4, r16 = lane & 15;

#pragma unroll
  for (int i = 0; i < 10; ++i) {
    int chunk = i * 8 + wave;
    if (chunk < WCHUNKS) {
      int off = chunk * 512 + lane * 8;
      __builtin_amdgcn_global_load_lds((const GLOBAL_AS u32*)&wg[off],
                                       (LDS_AS u32*)&lds[off], 16, 0, 0);
    }
  }

  int n0 = blockIdx.x * 128;
  int rowA = n0 + wave * 16 + r16;
  bool valid = rowA < NN;
  float4 f[8];
#pragma unroll
  for (int ks = 0; ks < 4; ++ks) {
    if (valid) {
      const float4* fp = (const float4*)&feat[(size_t)rowA * 128 + ks * 32 + quad * 8];
      f[ks * 2] = fp[0];
      f[ks * 2 + 1] = fp[1];
    } else {
      f[ks * 2] = make_float4(0.f, 0.f, 0.f, 0.f);
      f[ks * 2 + 1] = f[ks * 2];
    }
  }
  __syncthreads();

  f32x4 acc[9];
#pragma unroll
  for (int nt = 0; nt < 9; nt++) acc[nt] = (f32x4)0.f;

#pragma unroll
  for (int ks = 0; ks < 4; ks++) {
    bf16x8 ah, al;
    {
      float4 va = f[ks * 2], vb = f[ks * 2 + 1];
      float vv[8] = {va.x, va.y, va.z, va.w, vb.x, vb.y, vb.z, vb.w};
      us8 hh, ll;
#pragma unroll
      for (int j = 0; j < 8; j++) {
        ushort hb = f2bf(vv[j]);
        float hf = __uint_as_float(((unsigned)hb) << 16);
        hh[j] = hb;
        ll[j] = (ushort)(__float_as_uint(vv[j] - hf) >> 16);
      }
      ah = (bf16x8)hh;
      al = (bf16x8)ll;
    }
    int cc = ks * 4 + quad;
#pragma unroll
    for (int nt = 0; nt < 9; nt++) {
      int wrow = (nt < 8) ? (nt * 16 + r16) : (128 + r16);
      bf16x8 bh = *(const bf16x8*)&lds[((size_t)cc * WROWS + wrow) * 8];
      bf16x8 bl = *(const bf16x8*)&lds[((size_t)(16 + cc) * WROWS + wrow) * 8];
      acc[nt] = __builtin_amdgcn_mfma_f32_16x16x32_bf16(ah, bh, acc[nt], 0, 0, 0);
      acc[nt] = __builtin_amdgcn_mfma_f32_16x16x32_bf16(al, bh, acc[nt], 0, 0, 0);
      acc[nt] = __builtin_amdgcn_mfma_f32_16x16x32_bf16(ah, bl, acc[nt], 0, 0, 0);
    }
  }

#pragma unroll
  for (int reg = 0; reg < 4; reg++) {
    float am = 0.f;
#pragma unroll
    for (int nt = 0; nt < 8; nt++) am = fmaxf(am, fabsf(acc[nt][reg]));
#pragma unroll
    for (int off = 1; off < 16; off <<= 1) am = fmaxf(am, __shfl_xor(am, off));
    int node = n0 + wave * 16 + quad * 4 + reg;
    if (node < NN) {
      float amc = fmaxf(am, 1e-20f);
      float rq = 32767.f / amc;
      if (r16 < 4) asp[node * 8 + r16] = acc[8][reg];
      else if (r16 < 8) adstf[node * 4 + r16 - 4] = acc[8][reg];
      else if (r16 == 8) asp[node * 8 + 4] = amc * (1.f / 32767.f);
      short* dq = &hq[(size_t)node * 128 + r16];
#pragma unroll
      for (int nt = 0; nt < 8; nt++)
        dq[nt * 16] = (short)__float2int_rn(acc[nt][reg] * rq);
    }
  }
}

// ---------------- gather-aggregate: 3-deep pipeline (srcs r+2 | asp r+1 | consume r) ----------------
__global__ __launch_bounds__(256) void k_gather(const short* __restrict__ hq,
    const float* __restrict__ asp,
    const float4* __restrict__ adst,
    const int* __restrict__ cursor, const ushort* __restrict__ srcs,
    const float* __restrict__ bias, float* __restrict__ outf) {
  __shared__ alignas(16) int   s_src[2][4][4][16];
  __shared__ alignas(16) float s_wt[2][4][4][4][20];

  int wave = threadIdx.x >> 6, lane = threadIdx.x & 63;
  int grp = lane >> 4;
  int gl = lane & 15;
  int node = blockIdx.x * 16 + wave * 4 + grp;
  int head = gl >> 2;
  int c0 = gl << 3;

  int deg = 0, e0 = 0;
  float4 ad = make_float4(0.f, 0.f, 0.f, 0.f);
  bool valid = node < NN;
  if (valid) {
    deg = min(cursor[node], STRIDE);
    e0 = node << 6;
    ad = adst[node];
  }
  int rounds = (deg + 15) >> 4;

  float acc[8];
#pragma unroll
  for (int i = 0; i < 8; i++) acc[i] = 0.f;
  float ws0 = 0.f, ws1 = 0.f, ws2 = 0.f, ws3 = 0.f;
  float wself = 0.f;

  auto loadSrc = [&](int r, int& sn, int& lv) {
    int j = (r << 4) + gl;
    lv = (j < deg);
    sn = lv ? (int)srcs[e0 + j] : 0;
  };
  auto loadAsp = [&](int sn, int lv, float4& a, float& sc) {
    if (lv) {
      a = *(const float4*)&asp[sn * 8];
      sc = asp[sn * 8 + 4];
    } else {
      a = make_float4(0.f, 0.f, 0.f, 0.f);
      sc = 0.f;
    }
  };
  auto finishWrite = [&](int b, int sn, int lv, float4 a, float sc) {
    float q0 = 0.f, q1 = 0.f, q2 = 0.f, q3 = 0.f;
    if (lv) {
      float v, w0, w1, w2, w3;
      v = a.x + ad.x; v = v > 0.f ? v : NEG * v; w0 = __expf(v);
      v = a.y + ad.y; v = v > 0.f ? v : NEG * v; w1 = __expf(v);
      v = a.z + ad.z; v = v > 0.f ? v : NEG * v; w2 = __expf(v);
      v = a.w + ad.w; v = v > 0.f ? v : NEG * v; w3 = __expf(v);
      ws0 += w0; ws1 += w1; ws2 += w2; ws3 += w3;
      q0 = w0 * sc; q1 = w1 * sc; q2 = w2 * sc; q3 = w3 * sc;
    }
    s_src[b][wave][grp][gl] = sn << 7;
    s_wt[b][wave][grp][0][gl] = q0;
    s_wt[b][wave][grp][1][gl] = q1;
    s_wt[b][wave][grp][2][gl] = q2;
    s_wt[b][wave][grp][3][gl] = q3;
  };

  auto consume = [&](int r, int b) {
    int cnt2 = deg - (r << 4);
    cnt2 = min(cnt2, 16);
    const int* srow = &s_src[b][wave][grp][0];
    const float* wrow = &s_wt[b][wave][grp][head][0];
#pragma unroll
    for (int c = 0; c < 2; ++c) {
      int k0 = c << 3;
      if (k0 < cnt2) {
        int4 sa = *(const int4*)&srow[k0];
        int4 sb = *(const int4*)&srow[k0 + 4];
        float4 wa = *(const float4*)&wrow[k0];
        float4 wb = *(const float4*)&wrow[k0 + 4];
        s16x8 qa = *(const s16x8*)&hq[sa.x + c0];
        s16x8 qb = *(const s16x8*)&hq[sa.y + c0];
        s16x8 qc = *(const s16x8*)&hq[sa.z + c0];
        s16x8 qd = *(const s16x8*)&hq[sa.w + c0];
        s16x8 qe = *(const s16x8*)&hq[sb.x + c0];
        s16x8 qf = *(const s16x8*)&hq[sb.y + c0];
        s16x8 qg = *(const s16x8*)&hq[sb.z + c0];
        s16x8 qh = *(const s16x8*)&hq[sb.w + c0];
#pragma unroll
        for (int i = 0; i < 8; i++) acc[i] = fmaf(wa.x, (float)qa[i], acc[i]);
#pragma unroll
        for (int i = 0; i < 8; i++) acc[i] = fmaf(wa.y, (float)qb[i], acc[i]);
#pragma unroll
        for (int i = 0; i < 8; i++) acc[i] = fmaf(wa.z, (float)qc[i], acc[i]);
#pragma unroll
        for (int i = 0; i < 8; i++) acc[i] = fmaf(wa.w, (float)qd[i], acc[i]);
        if (k0 + 4 < cnt2) {
#pragma unroll
          for (int i = 0; i < 8; i++) acc[i] = fmaf(wb.x, (float)qe[i], acc[i]);
#pragma unroll
          for (int i = 0; i < 8; i++) acc[i] = fmaf(wb.y, (float)qf[i], acc[i]);
#pragma unroll
          for (int i = 0; i < 8; i++) acc[i] = fmaf(wb.z, (float)qg[i], acc[i]);
#pragma unroll
          for (int i = 0; i < 8; i++) acc[i] = fmaf(wb.w, (float)qh[i], acc[i]);
        }
      }
    }
  };

  // pipeline regs: sn1/lv1 = round r+1's srcs; sn2/lv2 = round r+2's
  int sn0 = 0, lv0 = 0, sn1 = 0, lv1 = 0, sn2 = 0, lv2 = 0;
  float4 a0; float sc0;

  if (rounds > 0) {
    loadSrc(0, sn0, lv0);                  // issue srcs(0)
    if (rounds > 1) loadSrc(1, sn1, lv1);  // issue srcs(1)
    loadAsp(sn0, lv0, a0, sc0);            // issue asp(0) (waits srcs(0))
  }

  // self-loop compute hides the pipeline-fill latency
  if (valid) {
    const float4 a = *(const float4*)&asp[node * 8];
    float sc = asp[node * 8 + 4];
    float v, w0, w1, w2, w3;
    v = a.x + ad.x; v = v > 0.f ? v : NEG * v; w0 = __expf(v);
    v = a.y + ad.y; v = v > 0.f ? v : NEG * v; w1 = __expf(v);
    v = a.z + ad.z; v = v > 0.f ? v : NEG * v; w2 = __expf(v);
    v = a.w + ad.w; v = v > 0.f ? v : NEG * v; w3 = __expf(v);
    float wh = (head == 0) ? w0 : (head == 1) ? w1 : (head == 2) ? w2 : w3;
    wself = wh;
    float wssc = wh * sc;
    s16x8 qs = *(const s16x8*)&hq[(node << 7) + c0];
#pragma unroll
    for (int i = 0; i < 8; i++) acc[i] = wssc * (float)qs[i];
  }

  if (rounds > 0) {
    finishWrite(0, sn0, lv0, a0, sc0);     // S3(0) -> buffer 0
    for (int r = 0; r < rounds; ++r) {
      int b = r & 1;
      if (r + 2 < rounds) loadSrc(r + 2, sn2, lv2);   // S1(r+2)
      float4 aX = make_float4(0.f, 0.f, 0.f, 0.f); float scX = 0.f;
      if (r + 1 < rounds) loadAsp(sn1, lv1, aX, scX); // S2(r+1): hidden under consume
      consume(r, b);                                  // S4(r)
      if (r + 1 < rounds) finishWrite(b ^ 1, sn1, lv1, aX, scX);  // S3(r+1)
      sn1 = sn2; lv1 = lv2;
    }
  }

#pragma unroll
  for (int off = 1; off < 16; off <<= 1) {
    ws0 += __shfl_xor(ws0, off);
    ws1 += __shfl_xor(ws1, off);
    ws2 += __shfl_xor(ws2, off);
    ws3 += __shfl_xor(ws3, off);
  }

  if (valid) {
    float wsum = wself + ((head == 0) ? ws0 : (head == 1) ? ws1 : (head == 2) ? ws2 : ws3);
    float rcp = 1.f / (wsum + 1e-16f);
    float4 bv0 = *(const float4*)&bias[c0];
    float4 bv1 = *(const float4*)&bias[c0 + 4];
    float bb[8] = {bv0.x, bv0.y, bv0.z, bv0.w, bv1.x, bv1.y, bv1.z, bv1.w};
    float o[8];
#pragma unroll
    for (int i = 0; i < 8; i++) {
      float v = acc[i] * rcp + bb[i];
      o[i] = v > 0.f ? v : expm1f(v);
    }
    *(float4*)&outf[(size_t)node * 128 + c0] = make_float4(o[0], o[1], o[2], o[3]);
    *(float4*)&outf[(size_t)node * 128 + c0 + 4] = make_float4(o[4], o[5], o[6], o[7]);
  }
}

// ---------------- mean pool (per-block local accumulation, few atomics) ----------------
__global__ __launch_bounds__(128) void k_pool(const float* __restrict__ feat,
    const int* __restrict__ batch, float* __restrict__ pooled, float* __restrict__ cnt) {
  int n0 = blockIdx.x * 32;
  int c = threadIdx.x;
  float acc = 0.f; int curg = -1;
  for (int i = 0; i < 32; i++) {
    int n = n0 + i;
    if (n >= NN) break;
    int g = batch[n];
    if (g != curg) {
      if (curg >= 0) atomicAdd(&pooled[curg * 128 + c], acc);
      acc = 0.f; curg = g;
    }
    acc += feat[n * 128 + c];
  }
  if (curg >= 0) atomicAdd(&pooled[curg * 128 + c], acc);
  if (threadIdx.x == 0) {
    float cc = 0.f; int cg = -1;
    for (int i = 0; i < 32; i++) {
      int n = n0 + i;
      if (n >= NN) break;
      int g = batch[n];
      if (g != cg) { if (cg >= 0) atomicAdd(&cnt[cg], cc); cc = 0.f; cg = g; }
      cc += 1.f;
    }
    if (cg >= 0) atomicAdd(&cnt[cg], cc);
  }
}

// ---------------- final FC ----------------
__global__ __launch_bounds__(128) void k_fc(const float* __restrict__ pooled,
    const float* __restrict__ cnt, const float* __restrict__ fcW,
    const float* __restrict__ fcb, float* __restrict__ out) {
  int g = blockIdx.x;
  __shared__ float p[128];
  int t = threadIdx.x;
  float inv = 1.0f / fmaxf(cnt[g], 1.0f);
  p[t] = pooled[g * 128 + t] * inv;
  __syncthreads();
  if (t < OUTC) {
    float acc = fcb[t];
    const float4* wr = (const float4*)&fcW[t * 128];
    const float4* pp = (const float4*)p;
#pragma unroll
    for (int i = 0; i < 32; i++) {
      float4 w = wr[i], pv = pp[i];
      acc = fmaf(w.x, pv.x, fmaf(w.y, pv.y, fmaf(w.z, pv.z, fmaf(w.w, pv.w, acc))));
    }
    out[g * OUTC + t] = acc;
  }
}

extern "C" void kernel_launch(void* const* d_in, const int* in_sizes, int n_in,
                              void* d_out, int out_size, void* d_ws, size_t ws_size,
                              hipStream_t stream) {
  const float* x    = (const float*)d_in[0];
  const int*   ei   = (const int*)d_in[1];
  const int*   batch= (const int*)d_in[2];
  const float* W1   = (const float*)d_in[3];
  const float* as1  = (const float*)d_in[4];
  const float* ad1  = (const float*)d_in[5];
  const float* b1   = (const float*)d_in[6];
  const float* W2   = (const float*)d_in[7];
  const float* as2  = (const float*)d_in[8];
  const float* ad2  = (const float*)d_in[9];
  const float* b2   = (const float*)d_in[10];
  const float* W3   = (const float*)d_in[11];
  const float* as3  = (const float*)d_in[12];
  const float* ad3  = (const float*)d_in[13];
  const float* b3   = (const float*)d_in[14];
  const float* fcW  = (const float*)d_in[15];
  const float* fcb  = (const float*)d_in[16];
  float* out = (float*)d_out;

  char* p = (char*)d_ws;
  auto alloc = [&](size_t bytes) { char* r = p; p += (bytes + 255) & ~(size_t)255; return r; };
  short* hq     = (short*)alloc((size_t)NN * 128 * 2);
  float* asp    = (float*)alloc((size_t)NN * 8 * 4);
  float* buf0   = (float*)alloc((size_t)NN * 128 * 4);
  float* adstv  = (float*)alloc((size_t)NN * 4 * 4);
  char*  zbase  = p;
  int*   cursor = (int*)alloc((size_t)NN * 4);
  float* pooled = (float*)alloc((size_t)GG * 128 * 4);
  float* cnt    = (float*)alloc((size_t)GG * 4);
  size_t zlen   = (size_t)(p - zbase);
  ushort* srcs  = (ushort*)alloc((size_t)NN * STRIDE * 2);
  ushort* wg    = (ushort*)alloc((size_t)3 * WLAYER * 2);

  hipMemsetAsync(zbase, 0, zlen, stream);

  k_scatter_prep<<<SCAT_BLOCKS + 204, 256, 0, stream>>>(ei, cursor, srcs,
      W1, W2, W3, as1, as2, as3, ad1, ad2, ad3, wg);

  const float* bs[3] = {b1, b2, b3};
  const float* fin = x;
  for (int l = 0; l < 3; l++) {
    k_gemm_mfma<<<(NN + 127) / 128, 512, 0, stream>>>(fin,
        wg + (size_t)l * WLAYER, hq, asp, adstv);
    k_gather<<<(NN + 15) / 16, 256, 0, stream>>>(hq, asp,
        (const float4*)adstv, cursor, srcs, bs[l], buf0);
    fin = buf0;
  }
  k_pool<<<(NN + 31) / 32, 128, 0, stream>>>(buf0, batch, pooled, cnt);
  k_fc<<<GG, 128, 0, stream>>>(pooled, cnt, fcW, fcb, out);
}

// Round 7
// 320.758 us; speedup vs baseline: 1.1079x; 1.0054x over previous
//
#include <hip/hip_runtime.h>
#include <math.h>

#define NN 50000
#define EE 800000
#define GG 512
#define OUTC 100
#define NEG 0.2f
#define STRIDE 64
#define NPART 8
#define PRNG (NN / NPART)           // 6250
#define PCHUNK 4096
#define NCHUNK 196                  // 196*4096 >= 800000
#define SCAT_BLOCKS (NPART * NCHUNK)   // 1568, %8==0

// cursor is padded to one counter per 64B line (stride 16 ints) to kill
// same-line L2 atomic serialization (16 random-dst counters/line otherwise).
#define CSTRIDE 16

// weight block layout: 32 sub-blocks (16 hi + 16 lo) x WROWS rows x 8 ushorts.
#define WROWS 145
#define WCHUNKS 73
#define WLAYER (WCHUNKS * 512)

typedef unsigned int u32;
#define GLOBAL_AS __attribute__((address_space(1)))
#define LDS_AS __attribute__((address_space(3)))

typedef __attribute__((ext_vector_type(8))) short bf16x8;
typedef __attribute__((ext_vector_type(8))) short s16x8;
typedef __attribute__((ext_vector_type(8))) unsigned short us8;
typedef __attribute__((ext_vector_type(4))) float f32x4;
typedef __attribute__((ext_vector_type(4))) int i32x4;

__device__ inline ushort f2bf(float v) {
  unsigned u = __float_as_uint(v);
  unsigned r = (u + 0x7fff + ((u >> 16) & 1)) >> 16;
  return (ushort)r;
}

// ---- dst-partitioned scatter (round-4 inner loop + padded cursor) + weight prep ----
__global__ __launch_bounds__(256) void k_scatter_prep(const int* __restrict__ ei,
    int* __restrict__ cursor, ushort* __restrict__ srcs,
    const float* __restrict__ W0, const float* __restrict__ W1, const float* __restrict__ W2,
    const float* __restrict__ as0, const float* __restrict__ as1, const float* __restrict__ as2,
    const float* __restrict__ ad0, const float* __restrict__ ad1, const float* __restrict__ ad2,
    ushort* __restrict__ wg) {
  if (blockIdx.x < SCAT_BLOCKS) {
    int part = blockIdx.x & (NPART - 1);     // == XCD under round-robin placement
    int chunk = blockIdx.x >> 3;
    int plo = part * PRNG, phi = plo + PRNG;
    int base = chunk * PCHUNK + (threadIdx.x << 2);
    int4 d[4];
    bool lv[4];
#pragma unroll
    for (int it = 0; it < 4; ++it) {         // issue all dst loads up-front
      int e = base + (it << 10);
      lv[it] = (e < EE);                     // EE%4==0 && e%4==0 -> full int4 safe
      if (lv[it]) d[it] = *(const int4*)&ei[EE + e];
      else        d[it] = make_int4(-1, -1, -1, -1);
    }
#pragma unroll
    for (int it = 0; it < 4; ++it) {
      if (!lv[it]) continue;
      int e = base + (it << 10);
      int4 dd = d[it];
      bool m0 = (dd.x >= plo) & (dd.x < phi);
      bool m1 = (dd.y >= plo) & (dd.y < phi);
      bool m2 = (dd.z >= plo) & (dd.z < phi);
      bool m3 = (dd.w >= plo) & (dd.w < phi);
      if (m0 | m1 | m2 | m3) {
        int4 s4 = *(const int4*)&ei[e];
        if (m0) { int p = atomicAdd(&cursor[dd.x * CSTRIDE], 1); if (p < STRIDE) srcs[(dd.x << 6) + p] = (ushort)s4.x; }
        if (m1) { int p = atomicAdd(&cursor[dd.y * CSTRIDE], 1); if (p < STRIDE) srcs[(dd.y << 6) + p] = (ushort)s4.y; }
        if (m2) { int p = atomicAdd(&cursor[dd.z * CSTRIDE], 1); if (p < STRIDE) srcs[(dd.z << 6) + p] = (ushort)s4.z; }
        if (m3) { int p = atomicAdd(&cursor[dd.w * CSTRIDE], 1); if (p < STRIDE) srcs[(dd.w << 6) + p] = (ushort)s4.w; }
      }
    }
  } else {
    int pb = blockIdx.x - SCAT_BLOCKS;          // 0..203
    int layer = pb / 68, bx = pb % 68;
    const float* W  = (layer == 0) ? W0 : (layer == 1) ? W1 : W2;
    const float* av = (layer == 0) ? as0 : (layer == 1) ? as1 : as2;
    const float* dv = (layer == 0) ? ad0 : (layer == 1) ? ad1 : ad2;
    ushort* wgL = wg + (size_t)layer * WLAYER;
    int idx = bx * 256 + threadIdx.x;
    if (bx < 64) {
      int row = idx >> 7, col = idx & 127;
      int c = col >> 3, j = col & 7;
      float v = W[idx];
      ushort hb = f2bf(v);
      float hf = __uint_as_float(((unsigned)hb) << 16);
      wgL[((size_t)c * WROWS + row) * 8 + j] = hb;
      wgL[((size_t)(16 + c) * WROWS + row) * 8 + j] = f2bf(v - hf);
    } else {
      int j2 = idx - 64 * 256;                  // [0,1024)
      int j = j2 >> 7, k = j2 & 127;            // j: attn row 0..7, k: col
      int head = j & 3;
      const float* vec = (j < 4) ? &av[head * 32] : &dv[head * 32];
      float dot = 0.f;
#pragma unroll
      for (int c = 0; c < 32; c++) dot += W[(head * 32 + c) * 128 + k] * vec[c];
      ushort hb = f2bf(dot);
      float hf = __uint_as_float(((unsigned)hb) << 16);
      int c16 = k >> 3, jj = k & 7;
      wgL[((size_t)c16 * WROWS + 128 + j) * 8 + jj] = hb;
      wgL[((size_t)(16 + c16) * WROWS + 128 + j) * 8 + jj] = f2bf(dot - hf);
      wgL[((size_t)c16 * WROWS + 136 + j) * 8 + jj] = 0;
      wgL[((size_t)(16 + c16) * WROWS + 136 + j) * 8 + jj] = 0;
    }
  }
}

// ---------------- GEMM: weights staged in LDS, feat hoisted to regs ----------------
__global__ __launch_bounds__(512) void k_gemm_mfma(const float* __restrict__ feat,
    const ushort* __restrict__ wg,
    short* __restrict__ hq, float* __restrict__ asp, float* __restrict__ adstf) {
  __shared__ alignas(16) ushort lds[WLAYER];
  int t = threadIdx.x;
  int wave = t >> 6, lane = t & 63;
  int quad = lane >> 4, r16 = lane & 15;

#pragma unroll
  for (int i = 0; i < 10; ++i) {
    int chunk = i * 8 + wave;
    if (chunk < WCHUNKS) {
      int off = chunk * 512 + lane * 8;
      __builtin_amdgcn_global_load_lds((const GLOBAL_AS u32*)&wg[off],
                                       (LDS_AS u32*)&lds[off], 16, 0, 0);
    }
  }

  int n0 = blockIdx.x * 128;
  int rowA = n0 + wave * 16 + r16;
  bool valid = rowA < NN;
  float4 f[8];
#pragma unroll
  for (int ks = 0; ks < 4; ++ks) {
    if (valid) {
      const float4* fp = (const float4*)&feat[(size_t)rowA * 128 + ks * 32 + quad * 8];
      f[ks * 2] = fp[0];
      f[ks * 2 + 1] = fp[1];
    } else {
      f[ks * 2] = make_float4(0.f, 0.f, 0.f, 0.f);
      f[ks * 2 + 1] = f[ks * 2];
    }
  }
  __syncthreads();

  f32x4 acc[9];
#pragma unroll
  for (int nt = 0; nt < 9; nt++) acc[nt] = (f32x4)0.f;

#pragma unroll
  for (int ks = 0; ks < 4; ks++) {
    bf16x8 ah, al;
    {
      float4 va = f[ks * 2], vb = f[ks * 2 + 1];
      float vv[8] = {va.x, va.y, va.z, va.w, vb.x, vb.y, vb.z, vb.w};
      us8 hh, ll;
#pragma unroll
      for (int j = 0; j < 8; j++) {
        ushort hb = f2bf(vv[j]);
        float hf = __uint_as_float(((unsigned)hb) << 16);
        hh[j] = hb;
        ll[j] = (ushort)(__float_as_uint(vv[j] - hf) >> 16);
      }
      ah = (bf16x8)hh;
      al = (bf16x8)ll;
    }
    int cc = ks * 4 + quad;
#pragma unroll
    for (int nt = 0; nt < 9; nt++) {
      int wrow = (nt < 8) ? (nt * 16 + r16) : (128 + r16);
      bf16x8 bh = *(const bf16x8*)&lds[((size_t)cc * WROWS + wrow) * 8];
      bf16x8 bl = *(const bf16x8*)&lds[((size_t)(16 + cc) * WROWS + wrow) * 8];
      acc[nt] = __builtin_amdgcn_mfma_f32_16x16x32_bf16(ah, bh, acc[nt], 0, 0, 0);
      acc[nt] = __builtin_amdgcn_mfma_f32_16x16x32_bf16(al, bh, acc[nt], 0, 0, 0);
      acc[nt] = __builtin_amdgcn_mfma_f32_16x16x32_bf16(ah, bl, acc[nt], 0, 0, 0);
    }
  }

#pragma unroll
  for (int reg = 0; reg < 4; reg++) {
    float am = 0.f;
#pragma unroll
    for (int nt = 0; nt < 8; nt++) am = fmaxf(am, fabsf(acc[nt][reg]));
#pragma unroll
    for (int off = 1; off < 16; off <<= 1) am = fmaxf(am, __shfl_xor(am, off));
    int node = n0 + wave * 16 + quad * 4 + reg;
    if (node < NN) {
      float amc = fmaxf(am, 1e-20f);
      float rq = 32767.f / amc;
      if (r16 < 4) asp[node * 8 + r16] = acc[8][reg];
      else if (r16 < 8) adstf[node * 4 + r16 - 4] = acc[8][reg];
      else if (r16 == 8) asp[node * 8 + 4] = amc * (1.f / 32767.f);
      short* dq = &hq[(size_t)node * 128 + r16];
#pragma unroll
      for (int nt = 0; nt < 8; nt++)
        dq[nt * 16] = (short)__float2int_rn(acc[nt][reg] * rq);
    }
  }
}

// ---------------- gather-aggregate: 3-deep pipeline (srcs r+2 | asp r+1 | consume r) ----------------
__global__ __launch_bounds__(256) void k_gather(const short* __restrict__ hq,
    const float* __restrict__ asp,
    const float4* __restrict__ adst,
    const int* __restrict__ cursor, const ushort* __restrict__ srcs,
    const float* __restrict__ bias, float* __restrict__ outf) {
  __shared__ alignas(16) int   s_src[2][4][4][16];
  __shared__ alignas(16) float s_wt[2][4][4][4][20];

  int wave = threadIdx.x >> 6, lane = threadIdx.x & 63;
  int grp = lane >> 4;
  int gl = lane & 15;
  int node = blockIdx.x * 16 + wave * 4 + grp;
  int head = gl >> 2;
  int c0 = gl << 3;

  int deg = 0, e0 = 0;
  float4 ad = make_float4(0.f, 0.f, 0.f, 0.f);
  bool valid = node < NN;
  if (valid) {
    deg = min(cursor[node * CSTRIDE], STRIDE);
    e0 = node << 6;
    ad = adst[node];
  }
  int rounds = (deg + 15) >> 4;

  float acc[8];
#pragma unroll
  for (int i = 0; i < 8; i++) acc[i] = 0.f;
  float ws0 = 0.f, ws1 = 0.f, ws2 = 0.f, ws3 = 0.f;
  float wself = 0.f;

  auto loadSrc = [&](int r, int& sn, int& lv) {
    int j = (r << 4) + gl;
    lv = (j < deg);
    sn = lv ? (int)srcs[e0 + j] : 0;
  };
  auto loadAsp = [&](int sn, int lv, float4& a, float& sc) {
    if (lv) {
      a = *(const float4*)&asp[sn * 8];
      sc = asp[sn * 8 + 4];
    } else {
      a = make_float4(0.f, 0.f, 0.f, 0.f);
      sc = 0.f;
    }
  };
  auto finishWrite = [&](int b, int sn, int lv, float4 a, float sc) {
    float q0 = 0.f, q1 = 0.f, q2 = 0.f, q3 = 0.f;
    if (lv) {
      float v, w0, w1, w2, w3;
      v = a.x + ad.x; v = v > 0.f ? v : NEG * v; w0 = __expf(v);
      v = a.y + ad.y; v = v > 0.f ? v : NEG * v; w1 = __expf(v);
      v = a.z + ad.z; v = v > 0.f ? v : NEG * v; w2 = __expf(v);
      v = a.w + ad.w; v = v > 0.f ? v : NEG * v; w3 = __expf(v);
      ws0 += w0; ws1 += w1; ws2 += w2; ws3 += w3;
      q0 = w0 * sc; q1 = w1 * sc; q2 = w2 * sc; q3 = w3 * sc;
    }
    s_src[b][wave][grp][gl] = sn << 7;
    s_wt[b][wave][grp][0][gl] = q0;
    s_wt[b][wave][grp][1][gl] = q1;
    s_wt[b][wave][grp][2][gl] = q2;
    s_wt[b][wave][grp][3][gl] = q3;
  };

  auto consume = [&](int r, int b) {
    int cnt2 = deg - (r << 4);
    cnt2 = min(cnt2, 16);
    const int* srow = &s_src[b][wave][grp][0];
    const float* wrow = &s_wt[b][wave][grp][head][0];
#pragma unroll
    for (int c = 0; c < 2; ++c) {
      int k0 = c << 3;
      if (k0 < cnt2) {
        int4 sa = *(const int4*)&srow[k0];
        int4 sb = *(const int4*)&srow[k0 + 4];
        float4 wa = *(const float4*)&wrow[k0];
        float4 wb = *(const float4*)&wrow[k0 + 4];
        s16x8 qa = *(const s16x8*)&hq[sa.x + c0];
        s16x8 qb = *(const s16x8*)&hq[sa.y + c0];
        s16x8 qc = *(const s16x8*)&hq[sa.z + c0];
        s16x8 qd = *(const s16x8*)&hq[sa.w + c0];
        s16x8 qe = *(const s16x8*)&hq[sb.x + c0];
        s16x8 qf = *(const s16x8*)&hq[sb.y + c0];
        s16x8 qg = *(const s16x8*)&hq[sb.z + c0];
        s16x8 qh = *(const s16x8*)&hq[sb.w + c0];
#pragma unroll
        for (int i = 0; i < 8; i++) acc[i] = fmaf(wa.x, (float)qa[i], acc[i]);
#pragma unroll
        for (int i = 0; i < 8; i++) acc[i] = fmaf(wa.y, (float)qb[i], acc[i]);
#pragma unroll
        for (int i = 0; i < 8; i++) acc[i] = fmaf(wa.z, (float)qc[i], acc[i]);
#pragma unroll
        for (int i = 0; i < 8; i++) acc[i] = fmaf(wa.w, (float)qd[i], acc[i]);
        if (k0 + 4 < cnt2) {
#pragma unroll
          for (int i = 0; i < 8; i++) acc[i] = fmaf(wb.x, (float)qe[i], acc[i]);
#pragma unroll
          for (int i = 0; i < 8; i++) acc[i] = fmaf(wb.y, (float)qf[i], acc[i]);
#pragma unroll
          for (int i = 0; i < 8; i++) acc[i] = fmaf(wb.z, (float)qg[i], acc[i]);
#pragma unroll
          for (int i = 0; i < 8; i++) acc[i] = fmaf(wb.w, (float)qh[i], acc[i]);
        }
      }
    }
  };

  int sn0 = 0, lv0 = 0, sn1 = 0, lv1 = 0, sn2 = 0, lv2 = 0;
  float4 a0; float sc0;

  if (rounds > 0) {
    loadSrc(0, sn0, lv0);
    if (rounds > 1) loadSrc(1, sn1, lv1);
    loadAsp(sn0, lv0, a0, sc0);
  }

  if (valid) {
    const float4 a = *(const float4*)&asp[node * 8];
    float sc = asp[node * 8 + 4];
    float v, w0, w1, w2, w3;
    v = a.x + ad.x; v = v > 0.f ? v : NEG * v; w0 = __expf(v);
    v = a.y + ad.y; v = v > 0.f ? v : NEG * v; w1 = __expf(v);
    v = a.z + ad.z; v = v > 0.f ? v : NEG * v; w2 = __expf(v);
    v = a.w + ad.w; v = v > 0.f ? v : NEG * v; w3 = __expf(v);
    float wh = (head == 0) ? w0 : (head == 1) ? w1 : (head == 2) ? w2 : w3;
    wself = wh;
    float wssc = wh * sc;
    s16x8 qs = *(const s16x8*)&hq[(node << 7) + c0];
#pragma unroll
    for (int i = 0; i < 8; i++) acc[i] = wssc * (float)qs[i];
  }

  if (rounds > 0) {
    finishWrite(0, sn0, lv0, a0, sc0);
    for (int r = 0; r < rounds; ++r) {
      int b = r & 1;
      if (r + 2 < rounds) loadSrc(r + 2, sn2, lv2);
      float4 aX = make_float4(0.f, 0.f, 0.f, 0.f); float scX = 0.f;
      if (r + 1 < rounds) loadAsp(sn1, lv1, aX, scX);
      consume(r, b);
      if (r + 1 < rounds) finishWrite(b ^ 1, sn1, lv1, aX, scX);
      sn1 = sn2; lv1 = lv2;
    }
  }

#pragma unroll
  for (int off = 1; off < 16; off <<= 1) {
    ws0 += __shfl_xor(ws0, off);
    ws1 += __shfl_xor(ws1, off);
    ws2 += __shfl_xor(ws2, off);
    ws3 += __shfl_xor(ws3, off);
  }

  if (valid) {
    float wsum = wself + ((head == 0) ? ws0 : (head == 1) ? ws1 : (head == 2) ? ws2 : ws3);
    float rcp = 1.f / (wsum + 1e-16f);
    float4 bv0 = *(const float4*)&bias[c0];
    float4 bv1 = *(const float4*)&bias[c0 + 4];
    float bb[8] = {bv0.x, bv0.y, bv0.z, bv0.w, bv1.x, bv1.y, bv1.z, bv1.w};
    float o[8];
#pragma unroll
    for (int i = 0; i < 8; i++) {
      float v = acc[i] * rcp + bb[i];
      o[i] = v > 0.f ? v : expm1f(v);
    }
    *(float4*)&outf[(size_t)node * 128 + c0] = make_float4(o[0], o[1], o[2], o[3]);
    *(float4*)&outf[(size_t)node * 128 + c0 + 4] = make_float4(o[4], o[5], o[6], o[7]);
  }
}

// ---------------- mean pool ----------------
__global__ __launch_bounds__(128) void k_pool(const float* __restrict__ feat,
    const int* __restrict__ batch, float* __restrict__ pooled, float* __restrict__ cnt) {
  int n0 = blockIdx.x * 32;
  int c = threadIdx.x;
  float acc = 0.f; int curg = -1;
  for (int i = 0; i < 32; i++) {
    int n = n0 + i;
    if (n >= NN) break;
    int g = batch[n];
    if (g != curg) {
      if (curg >= 0) atomicAdd(&pooled[curg * 128 + c], acc);
      acc = 0.f; curg = g;
    }
    acc += feat[n * 128 + c];
  }
  if (curg >= 0) atomicAdd(&pooled[curg * 128 + c], acc);
  if (threadIdx.x == 0) {
    float cc = 0.f; int cg = -1;
    for (int i = 0; i < 32; i++) {
      int n = n0 + i;
      if (n >= NN) break;
      int g = batch[n];
      if (g != cg) { if (cg >= 0) atomicAdd(&cnt[cg], cc); cc = 0.f; cg = g; }
      cc += 1.f;
    }
    if (cg >= 0) atomicAdd(&cnt[cg], cc);
  }
}

// ---------------- final FC ----------------
__global__ __launch_bounds__(128) void k_fc(const float* __restrict__ pooled,
    const float* __restrict__ cnt, const float* __restrict__ fcW,
    const float* __restrict__ fcb, float* __restrict__ out) {
  int g = blockIdx.x;
  __shared__ float p[128];
  int t = threadIdx.x;
  float inv = 1.0f / fmaxf(cnt[g], 1.0f);
  p[t] = pooled[g * 128 + t] * inv;
  __syncthreads();
  if (t < OUTC) {
    float acc = fcb[t];
    const float4* wr = (const float4*)&fcW[t * 128];
    const float4* pp = (const float4*)p;
#pragma unroll
    for (int i = 0; i < 32; i++) {
      float4 w = wr[i], pv = pp[i];
      acc = fmaf(w.x, pv.x, fmaf(w.y, pv.y, fmaf(w.z, pv.z, fmaf(w.w, pv.w, acc))));
    }
    out[g * OUTC + t] = acc;
  }
}

extern "C" void kernel_launch(void* const* d_in, const int* in_sizes, int n_in,
                              void* d_out, int out_size, void* d_ws, size_t ws_size,
                              hipStream_t stream) {
  const float* x    = (const float*)d_in[0];
  const int*   ei   = (const int*)d_in[1];
  const int*   batch= (const int*)d_in[2];
  const float* W1   = (const float*)d_in[3];
  const float* as1  = (const float*)d_in[4];
  const float* ad1  = (const float*)d_in[5];
  const float* b1   = (const float*)d_in[6];
  const float* W2   = (const float*)d_in[7];
  const float* as2  = (const float*)d_in[8];
  const float* ad2  = (const float*)d_in[9];
  const float* b2   = (const float*)d_in[10];
  const float* W3   = (const float*)d_in[11];
  const float* as3  = (const float*)d_in[12];
  const float* ad3  = (const float*)d_in[13];
  const float* b3   = (const float*)d_in[14];
  const float* fcW  = (const float*)d_in[15];
  const float* fcb  = (const float*)d_in[16];
  float* out = (float*)d_out;

  char* p = (char*)d_ws;
  auto alloc = [&](size_t bytes) { char* r = p; p += (bytes + 255) & ~(size_t)255; return r; };
  short* hq     = (short*)alloc((size_t)NN * 128 * 2);
  float* asp    = (float*)alloc((size_t)NN * 8 * 4);
  float* buf0   = (float*)alloc((size_t)NN * 128 * 4);
  float* adstv  = (float*)alloc((size_t)NN * 4 * 4);
  char*  zbase  = p;
  int*   cursor = (int*)alloc((size_t)NN * CSTRIDE * 4);   // 64B line per node
  float* pooled = (float*)alloc((size_t)GG * 128 * 4);
  float* cnt    = (float*)alloc((size_t)GG * 4);
  size_t zlen   = (size_t)(p - zbase);
  ushort* srcs  = (ushort*)alloc((size_t)NN * STRIDE * 2);
  ushort* wg    = (ushort*)alloc((size_t)3 * WLAYER * 2);

  hipMemsetAsync(zbase, 0, zlen, stream);

  k_scatter_prep<<<SCAT_BLOCKS + 204, 256, 0, stream>>>(ei, cursor, srcs,
      W1, W2, W3, as1, as2, as3, ad1, ad2, ad3, wg);

  const float* bs[3] = {b1, b2, b3};
  const float* fin = x;
  for (int l = 0; l < 3; l++) {
    k_gemm_mfma<<<(NN + 127) / 128, 512, 0, stream>>>(fin,
        wg + (size_t)l * WLAYER, hq, asp, adstv);
    k_gather<<<(NN + 15) / 16, 256, 0, stream>>>(hq, asp,
        (const float4*)adstv, cursor, srcs, bs[l], buf0);
    fin = buf0;
  }
  k_pool<<<(NN + 31) / 32, 128, 0, stream>>>(buf0, batch, pooled, cnt);
  k_fc<<<GG, 128, 0, stream>>>(pooled, cnt, fcW, fcb, out);
}